// Round 8
// baseline (998.383 us; speedup 1.0000x reference)
//
#include <hip/hip_runtime.h>
#include <cstdint>

#define T_TOKENS 8192
#define DMODEL 1024
#define DFF 4096
#define NEXP 8
#define NBPAD 72   // >= max sum_e ceil(count_e/256) = 71

typedef _Float16 f16x8 __attribute__((ext_vector_type(8)));
typedef float f32x4 __attribute__((ext_vector_type(4)));
using u16 = unsigned short;

__device__ __forceinline__ u16 f2h(float f) {
  union { _Float16 h; u16 u; } v; v.h = (_Float16)f; return v.u;
}

// async global->LDS, 16B per lane. LDS dest is wave-uniform base + lane*16.
__device__ __forceinline__ void async16(const void* g, void* l) {
  __builtin_amdgcn_global_load_lds(
      (const __attribute__((address_space(1))) unsigned int*)(uintptr_t)g,
      (__attribute__((address_space(3))) unsigned int*)(uint32_t)(uintptr_t)l,
      16, 0, 0);
}

// ---------------- gating: fp64-exact logits, top-2, scatter to expert lists --
__global__ __launch_bounds__(256) void gate_kernel(
    const float* __restrict__ x, const float* __restrict__ gumbel,
    const float* __restrict__ gate_w, const float* __restrict__ gate_b,
    int* __restrict__ counts, int* __restrict__ tok_list,
    int* __restrict__ tok_e, int* __restrict__ tok_p, float* __restrict__ tok_w)
{
  int t = blockIdx.x * 4 + (threadIdx.x >> 6);
  int lane = threadIdx.x & 63;
  const float* xr = x + (size_t)t * DMODEL;
  double acc[NEXP];
#pragma unroll
  for (int e = 0; e < NEXP; ++e) acc[e] = 0.0;
#pragma unroll
  for (int i = 0; i < DMODEL / 64; ++i) {
    int d = lane + i * 64;
    float xv = xr[d];
    const float4* gw = (const float4*)(gate_w + (size_t)d * NEXP);
    float4 g0 = gw[0], g1 = gw[1];
    acc[0] += (double)xv * (double)g0.x;
    acc[1] += (double)xv * (double)g0.y;
    acc[2] += (double)xv * (double)g0.z;
    acc[3] += (double)xv * (double)g0.w;
    acc[4] += (double)xv * (double)g1.x;
    acc[5] += (double)xv * (double)g1.y;
    acc[6] += (double)xv * (double)g1.z;
    acc[7] += (double)xv * (double)g1.w;
  }
#pragma unroll
  for (int e = 0; e < NEXP; ++e) {
    double v = acc[e];
    for (int off = 32; off > 0; off >>= 1) v += __shfl_down(v, off, 64);
    acc[e] = v;
  }
  if (lane == 0) {
    float noisy[NEXP];
#pragma unroll
    for (int e = 0; e < NEXP; ++e)
      noisy[e] = (float)(acc[e] + (double)gate_b[e]) + gumbel[(size_t)t * NEXP + e];
    int i0 = 0;
    for (int e = 1; e < NEXP; ++e) if (noisy[e] > noisy[i0]) i0 = e;
    int i1 = -1;
    for (int e = 0; e < NEXP; ++e) {
      if (e == i0) continue;
      if (i1 < 0 || noisy[e] > noisy[i1]) i1 = e;
    }
    float ex = expf(noisy[i1] - noisy[i0]);
    float w0 = 1.0f / (1.0f + ex);
    float w1 = ex / (1.0f + ex);
    int p0 = atomicAdd(&counts[i0], 1);
    tok_list[i0 * T_TOKENS + p0] = t;
    int p1 = atomicAdd(&counts[i1], 1);
    tok_list[i1 * T_TOKENS + p1] = t;
    tok_e[2 * t] = i0; tok_p[2 * t] = p0; tok_w[2 * t] = w0;
    tok_e[2 * t + 1] = i1; tok_p[2 * t + 1] = p1; tok_w[2 * t + 1] = w1;
  }
}

// offsets + compact live-block map: mb_map[i] = (e<<8)|bm, offs[8] = nb.
__global__ void offsets_kernel(const int* __restrict__ counts,
                               int* __restrict__ offs, int* __restrict__ mb_map) {
  if (threadIdx.x == 0 && blockIdx.x == 0) {
    int s = 0, nb = 0;
    for (int e = 0; e < NEXP; ++e) {
      offs[e] = s; s += counts[e];
      int nbe = (counts[e] + 255) >> 8;
      for (int b = 0; b < nbe; ++b) mb_map[nb++] = (e << 8) | b;
    }
    offs[8] = nb;
  }
}

__global__ __launch_bounds__(256) void slots_kernel(
    const int* __restrict__ offs, const int* __restrict__ tok_e,
    const int* __restrict__ tok_p, int* __restrict__ tok_slot)
{
  int i = blockIdx.x * 256 + threadIdx.x;
  if (i < 2 * T_TOKENS) tok_slot[i] = offs[tok_e[i]] + tok_p[i];
}

// ---------------- fp32 -> fp16 conversions -----------------------------------
__global__ __launch_bounds__(256) void cvt_f16_kernel(
    const float* __restrict__ in, u16* __restrict__ out, int n4)
{
  int i = blockIdx.x * 256 + threadIdx.x;
  if (i < n4) {
    float4 v = ((const float4*)in)[i];
    uint2 o;
    o.x = (unsigned)f2h(v.x) | ((unsigned)f2h(v.y) << 16);
    o.y = (unsigned)f2h(v.z) | ((unsigned)f2h(v.w) << 16);
    ((uint2*)out)[i] = o;
  }
}

// in [rows][cols] fp32 -> out [cols][rows] fp16, per-expert (blockIdx.z).
// R8 rewrite: in-register 4x4 transpose -> packed u32 LDS stores (~4-way,
// was 16-way scalar u16), vector uint2 LDS reads (~2-4 way), 32B/thread
// coalesced global writes. T row stride 68 u16 = 136B (8B aligned).
__global__ __launch_bounds__(256) void transpose_cvt_kernel(
    const float* __restrict__ in, u16* __restrict__ out, int rows, int cols)
{
  in  += (size_t)blockIdx.z * rows * cols;
  out += (size_t)blockIdx.z * rows * cols;
  int c0 = blockIdx.x * 64, r0 = blockIdx.y * 64;
  __shared__ u16 T[64][68];
  int tx = threadIdx.x & 15, ty = threadIdx.x >> 4;   // 16x16 threads
  int rr = ty * 4, cc = tx * 4;                       // 4x4 micro-tile
  const float* ip = &in[(size_t)(r0 + rr) * cols + (c0 + cc)];
  float4 v0 = *(const float4*)(ip);
  float4 v1 = *(const float4*)(ip + cols);
  float4 v2 = *(const float4*)(ip + 2 * (size_t)cols);
  float4 v3 = *(const float4*)(ip + 3 * (size_t)cols);
  const float* p0 = (const float*)&v0; const float* p1 = (const float*)&v1;
  const float* p2 = (const float*)&v2; const float* p3 = (const float*)&v3;
#pragma unroll
  for (int j = 0; j < 4; ++j) {
    union { u16 h[4]; unsigned u[2]; } pk;
    pk.h[0] = f2h(p0[j]); pk.h[1] = f2h(p1[j]);
    pk.h[2] = f2h(p2[j]); pk.h[3] = f2h(p3[j]);
    unsigned* dst = (unsigned*)&T[cc + j][rr];        // rr mult of 4 -> 4B ok
    dst[0] = pk.u[0];
    dst[1] = pk.u[1];
  }
  __syncthreads();
  int oc = threadIdx.x >> 2;                          // 0..63 (output col)
  int orr = (threadIdx.x & 3) * 16;                   // 0,16,32,48
  uint2 d0 = *(const uint2*)&T[oc][orr + 0];
  uint2 d1 = *(const uint2*)&T[oc][orr + 4];
  uint2 d2 = *(const uint2*)&T[oc][orr + 8];
  uint2 d3 = *(const uint2*)&T[oc][orr + 12];
  u16* op = &out[(size_t)(c0 + oc) * rows + (r0 + orr)];
  *(uint2*)(op + 0)  = d0;
  *(uint2*)(op + 4)  = d1;
  *(uint2*)(op + 8)  = d2;
  *(uint2*)(op + 12) = d3;
}

// =====================================================================
// 256x256 MFMA GEMMs: BK=32, 8 waves (2x4), 128x64 out/wave, 128KB quad
// buffer, single-barrier schedule (R7). R8: FULL-RANK XOR SWIZZLE.
// Old swizzle (^ row&3) left the fragment ds_read_b128 4-way bank-
// conflicted (rows r and r+4 alias: 8 same-parity rows over only 4
// 16B slots). Adding ^((r>>2)&3) makes the bank multiset uniform
// 2-per-bank = free (m136). Self-inverse XOR -> same term on the
// stage-side global offset (cg8) keeps the involution. Measured basis:
// 13.6M conflicts/dispatch = ~373 cyc/block-step of the 2400-cyc step.
// LDS-read-BW model: 96KB frag reads/step/CU @85B/cyc ~= 1130 cyc >>
// MFMA 310 cyc/SIMD -> MfmaUtil ceiling ~25% (matches all 4 schedule
// variants). Conflicts are the removable slice this round.
// =====================================================================

// ---------------- GEMM1: H = relu(X[gather] @ W1 + b1), fp16 out -------------
__global__ __launch_bounds__(512, 2) void gemm1_kernel(
    const u16* __restrict__ xh, const u16* __restrict__ w1t,
    const float* __restrict__ b1,
    const int* __restrict__ counts, const int* __restrict__ offs,
    const int* __restrict__ mb_map,
    const int* __restrict__ tok_list, u16* __restrict__ H)
{
  const int L = blockIdx.x;                  // 1152 = 8 * 144
  const int W = (L & 7) * 144 + (L >> 3);    // XCD-contiguous work id
  const int bn = W / NBPAD;                  // 0..15
  const int mbi = W - bn * NBPAD;
  const int nb = offs[8];
  if (mbi >= nb) return;
  const int pk = mb_map[mbi];
  const int e = pk >> 8, bm = pk & 255;
  const int count = counts[e];
  const int off = offs[e];

  __shared__ __align__(16) u16 sm[4][2][8192];   // quad buffer: 128KB

  const int tid = threadIdx.x;
  const int w = tid >> 6, lane = tid & 63;
  const int wm = w >> 2, wn = w & 3;               // wave grid 2(M) x 4(N)
  const int row16 = lane & 15, quad = lane >> 4;
  const int r = lane >> 2;
  // full-rank involution: slot = chunk ^ (r&3) ^ ((r>>2)&3)
  const int cg8 = (((lane & 3) ^ (r & 3) ^ ((r >> 2) & 3)) << 3);
  const int cm1 = count - 1;

  const u16* agA[2]; const u16* agB[2];
#pragma unroll
  for (int j = 0; j < 2; ++j) {
    int m = bm * 256 + w * 32 + j * 16 + r;        // 8 waves x 32 rows = 256
    int t = tok_list[e * T_TOKENS + (m < cm1 ? m : cm1)];
    agA[j] = xh + (size_t)t * DMODEL + cg8;
    int nrow = bn * 256 + w * 32 + j * 16 + r;
    agB[j] = w1t + ((size_t)e * DFF + nrow) * DMODEL + cg8;
  }
  const int ldsoff = w * 1024;                     // 32 rows * 32 cols per wave
  const int cslot = ((quad ^ (row16 & 3) ^ ((row16 >> 2) & 3)) << 3);

  f32x4 acc[8][4] = {};

#define STAGE1(k, b) { int ko = (k) << 5; \
    async16(agA[0] + ko, &sm[b][0][ldsoff]); \
    async16(agA[1] + ko, &sm[b][0][ldsoff + 512]); \
    async16(agB[0] + ko, &sm[b][1][ldsoff]); \
    async16(agB[1] + ko, &sm[b][1][ldsoff + 512]); }

  constexpr int NK = DMODEL / 32;   // 32
  STAGE1(0, 0); STAGE1(1, 1); STAGE1(2, 2);       // 12 loads in flight
  for (int k = 0; k < NK; ++k) {
    const int b = k & 3;
    // tiles k..k+2 outstanding (12); retire tile k, keep 8 in flight.
    asm volatile("s_waitcnt vmcnt(8)\n\ts_barrier" ::: "memory");
    STAGE1((k + 3) & (NK - 1), (k + 3) & 3);   // writes buf (k-1)&3: safe
    f16x8 af[8], bf[4];
#pragma unroll
    for (int f = 0; f < 8; ++f)
      af[f] = *(const f16x8*)&sm[b][0][(wm * 128 + f * 16 + row16) * 32 + cslot];
#pragma unroll
    for (int f = 0; f < 4; ++f)
      bf[f] = *(const f16x8*)&sm[b][1][(wn * 64 + f * 16 + row16) * 32 + cslot];
    __builtin_amdgcn_s_setprio(1);
#pragma unroll
    for (int fm = 0; fm < 8; ++fm)
#pragma unroll
      for (int fn = 0; fn < 4; ++fn)
        acc[fm][fn] = __builtin_amdgcn_mfma_f32_16x16x32_f16(bf[fn], af[fm], acc[fm][fn], 0, 0, 0);
    __builtin_amdgcn_s_setprio(0);
  }

  // lane holds m = wm*128+fm*16+row16 ; n = wn*64+fn*16+quad*4+{0..3}
  const int nb2 = bn * 256 + wn * 64 + quad * 4;
  const float* b1e = b1 + (size_t)e * DFF + nb2;
#pragma unroll
  for (int fm = 0; fm < 8; ++fm) {
    int m = bm * 256 + wm * 128 + fm * 16 + row16;
    if (m < count) {
      u16* hr = H + (size_t)(off + m) * DFF + nb2;
#pragma unroll
      for (int fn = 0; fn < 4; ++fn) {
        float4 bv = *(const float4*)(b1e + fn * 16);
        union { _Float16 h[4]; uint2 u; } pk2;
        float v0 = acc[fm][fn][0] + bv.x; pk2.h[0] = (_Float16)(v0 > 0.f ? v0 : 0.f);
        float v1 = acc[fm][fn][1] + bv.y; pk2.h[1] = (_Float16)(v1 > 0.f ? v1 : 0.f);
        float v2 = acc[fm][fn][2] + bv.z; pk2.h[2] = (_Float16)(v2 > 0.f ? v2 : 0.f);
        float v3 = acc[fm][fn][3] + bv.w; pk2.h[3] = (_Float16)(v3 > 0.f ? v3 : 0.f);
        *(uint2*)(hr + fn * 16) = pk2.u;
      }
    }
  }
}

// ---------------- GEMM2: P[slot] = H[slot] @ W2 + b2 (fp32, coalesced) -------
__global__ __launch_bounds__(512, 2) void gemm2_kernel(
    const u16* __restrict__ H, const u16* __restrict__ w2t,
    const float* __restrict__ b2,
    const int* __restrict__ counts, const int* __restrict__ offs,
    const int* __restrict__ mb_map,
    float* __restrict__ P)
{
  const int L = blockIdx.x;                  // 288 = 8 * 36
  const int W = (L & 7) * 36 + (L >> 3);     // XCD-contiguous work id
  const int mbi = W >> 2, bn = W & 3;        // 4 bn-siblings contiguous
  const int nb = offs[8];
  if (mbi >= nb) return;
  const int pk = mb_map[mbi];
  const int e = pk >> 8, bm = pk & 255;
  const int count = counts[e];
  const int off = offs[e];

  __shared__ __align__(16) u16 sm[4][2][8192];   // quad buffer: 128KB

  const int tid = threadIdx.x;
  const int w = tid >> 6, lane = tid & 63;
  const int wm = w >> 2, wn = w & 3;
  const int row16 = lane & 15, quad = lane >> 4;
  const int r = lane >> 2;
  const int cg8 = (((lane & 3) ^ (r & 3) ^ ((r >> 2) & 3)) << 3);
  const int cm1 = count - 1;

  const u16* agA[2]; const u16* agB[2];
#pragma unroll
  for (int j = 0; j < 2; ++j) {
    int m = bm * 256 + w * 32 + j * 16 + r;
    agA[j] = H + (size_t)(off + (m < cm1 ? m : cm1)) * DFF + cg8;
    int nrow = bn * 256 + w * 32 + j * 16 + r;
    agB[j] = w2t + ((size_t)e * DMODEL + nrow) * DFF + cg8;
  }
  const int ldsoff = w * 1024;
  const int cslot = ((quad ^ (row16 & 3) ^ ((row16 >> 2) & 3)) << 3);

  f32x4 acc[8][4] = {};

  constexpr int NK = DFF / 32;   // 128
  STAGE1(0, 0); STAGE1(1, 1); STAGE1(2, 2);       // 12 loads in flight
  for (int k = 0; k < NK; ++k) {
    const int b = k & 3;
    asm volatile("s_waitcnt vmcnt(8)\n\ts_barrier" ::: "memory");
    STAGE1((k + 3) & (NK - 1), (k + 3) & 3);   // writes buf (k-1)&3: safe
    f16x8 af[8], bf[4];
#pragma unroll
    for (int f = 0; f < 8; ++f)
      af[f] = *(const f16x8*)&sm[b][0][(wm * 128 + f * 16 + row16) * 32 + cslot];
#pragma unroll
    for (int f = 0; f < 4; ++f)
      bf[f] = *(const f16x8*)&sm[b][1][(wn * 64 + f * 16 + row16) * 32 + cslot];
    __builtin_amdgcn_s_setprio(1);
#pragma unroll
    for (int fm = 0; fm < 8; ++fm)
#pragma unroll
      for (int fn = 0; fn < 4; ++fn)
        acc[fm][fn] = __builtin_amdgcn_mfma_f32_16x16x32_f16(bf[fn], af[fm], acc[fm][fn], 0, 0, 0);
    __builtin_amdgcn_s_setprio(0);
  }

  const int nb2 = bn * 256 + wn * 64 + quad * 4;
  const float* b2e = b2 + (size_t)e * DMODEL + nb2;
#pragma unroll
  for (int fm = 0; fm < 8; ++fm) {
    int m = bm * 256 + wm * 128 + fm * 16 + row16;
    if (m < count) {
      float* pr = P + (size_t)(off + m) * DMODEL + nb2;
#pragma unroll
      for (int fn = 0; fn < 4; ++fn) {
        float4 bv = *(const float4*)(b2e + fn * 16);
        float4 o;
        o.x = acc[fm][fn][0] + bv.x;
        o.y = acc[fm][fn][1] + bv.y;
        o.z = acc[fm][fn][2] + bv.z;
        o.w = acc[fm][fn][3] + bv.w;
        *(float4*)(pr + fn * 16) = o;
      }
    }
  }
}

// ---------------- combine: out[t] = w0*P[s0] + w1*P[s1] ----------------------
__global__ __launch_bounds__(256) void combine_kernel(
    const float* __restrict__ P, const int* __restrict__ tok_slot,
    const float* __restrict__ tok_w, float* __restrict__ out)
{
  int idx = blockIdx.x * 256 + threadIdx.x;
  int t = idx >> 8;
  int d = (idx & 255) << 2;
  int s0 = tok_slot[2 * t], s1 = tok_slot[2 * t + 1];
  float w0 = tok_w[2 * t], w1 = tok_w[2 * t + 1];
  float4 a = *(const float4*)(P + (size_t)s0 * DMODEL + d);
  float4 b = *(const float4*)(P + (size_t)s1 * DMODEL + d);
  float4 o;
  o.x = w0 * a.x + w1 * b.x;
  o.y = w0 * a.y + w1 * b.y;
  o.z = w0 * a.z + w1 * b.z;
  o.w = w0 * a.w + w1 * b.w;
  *(float4*)(out + (size_t)t * DMODEL + d) = o;
}

// ---------------- launch -----------------------------------------------------
extern "C" void kernel_launch(void* const* d_in, const int* in_sizes, int n_in,
                              void* d_out, int out_size, void* d_ws, size_t ws_size,
                              hipStream_t stream)
{
  const float* x      = (const float*)d_in[0];
  const float* gumbel = (const float*)d_in[1];
  const float* gate_w = (const float*)d_in[2];
  const float* gate_b = (const float*)d_in[3];
  const float* w1     = (const float*)d_in[4];
  const float* b1     = (const float*)d_in[5];
  const float* w2     = (const float*)d_in[6];
  const float* b2     = (const float*)d_in[7];
  float* out = (float*)d_out;
  char* ws = (char*)d_ws;

  // workspace layout (~286 MB; P overlays dead w1t region)
  constexpr size_t OFF_COUNTS = 0;
  constexpr size_t OFF_OFFS   = 64;
  constexpr size_t OFF_MAP    = 128;     // 80 ints < (4096-128)
  constexpr size_t OFF_TOK    = 4096;
  constexpr size_t OFF_TE     = OFF_TOK + (size_t)NEXP * T_TOKENS * 4;
  constexpr size_t OFF_TP     = OFF_TE + 2 * T_TOKENS * 4;
  constexpr size_t OFF_TW     = OFF_TP + 2 * T_TOKENS * 4;
  constexpr size_t OFF_TS     = OFF_TW + 2 * T_TOKENS * 4;
  constexpr size_t OFF_XH     = OFF_TS + 2 * T_TOKENS * 4;
  constexpr size_t OFF_W1T    = OFF_XH  + (size_t)T_TOKENS * DMODEL * 2;
  constexpr size_t OFF_W2T    = OFF_W1T + (size_t)NEXP * DFF * DMODEL * 2;
  constexpr size_t OFF_H      = OFF_W2T + (size_t)NEXP * DMODEL * DFF * 2;
  constexpr size_t OFF_P      = OFF_W1T;  // w1t dead after gemm1

  int*   counts = (int*)(ws + OFF_COUNTS);
  int*   offs   = (int*)(ws + OFF_OFFS);
  int*   mb_map = (int*)(ws + OFF_MAP);
  int*   tokl   = (int*)(ws + OFF_TOK);
  int*   tok_e  = (int*)(ws + OFF_TE);
  int*   tok_p  = (int*)(ws + OFF_TP);
  float* tok_w  = (float*)(ws + OFF_TW);
  int*   tok_s  = (int*)(ws + OFF_TS);
  u16*   xh     = (u16*)(ws + OFF_XH);
  u16*   w1t    = (u16*)(ws + OFF_W1T);
  u16*   w2t    = (u16*)(ws + OFF_W2T);
  u16*   H      = (u16*)(ws + OFF_H);
  float* P      = (float*)(ws + OFF_P);

  hipMemsetAsync(ws + OFF_COUNTS, 0, 1024, stream);

  cvt_f16_kernel<<<(T_TOKENS * DMODEL / 4 + 255) / 256, 256, 0, stream>>>(
      x, xh, T_TOKENS * DMODEL / 4);
  transpose_cvt_kernel<<<dim3(DFF / 64, DMODEL / 64, NEXP), 256, 0, stream>>>(
      w1, w1t, DMODEL, DFF);
  transpose_cvt_kernel<<<dim3(DMODEL / 64, DFF / 64, NEXP), 256, 0, stream>>>(
      w2, w2t, DFF, DMODEL);
  gate_kernel<<<T_TOKENS / 4, 256, 0, stream>>>(
      x, gumbel, gate_w, gate_b, counts, tokl, tok_e, tok_p, tok_w);
  offsets_kernel<<<1, 64, 0, stream>>>(counts, offs, mb_map);
  slots_kernel<<<(2 * T_TOKENS + 255) / 256, 256, 0, stream>>>(
      offs, tok_e, tok_p, tok_s);
  gemm1_kernel<<<NBPAD * 16, 512, 0, stream>>>(
      xh, w1t, b1, counts, offs, mb_map, tokl, H);
  gemm2_kernel<<<NBPAD * 4, 512, 0, stream>>>(
      H, w2t, b2, counts, offs, mb_map, P);
  combine_kernel<<<T_TOKENS, 256, 0, stream>>>(P, tok_s, tok_w, out);
}

// Round 9
// 822.290 us; speedup vs baseline: 1.2141x; 1.2141x over previous
//
#include <hip/hip_runtime.h>
#include <cstdint>

#define T_TOKENS 8192
#define DMODEL 1024
#define DFF 4096
#define NEXP 8
#define NBPAD 72   // >= max sum_e ceil(count_e/256) = 71

typedef _Float16 f16x8 __attribute__((ext_vector_type(8)));
typedef float f32x4 __attribute__((ext_vector_type(4)));
using u16 = unsigned short;

__device__ __forceinline__ u16 f2h(float f) {
  union { _Float16 h; u16 u; } v; v.h = (_Float16)f; return v.u;
}

// async global->LDS, 16B per lane. LDS dest is wave-uniform base + lane*16.
__device__ __forceinline__ void async16(const void* g, void* l) {
  __builtin_amdgcn_global_load_lds(
      (const __attribute__((address_space(1))) unsigned int*)(uintptr_t)g,
      (__attribute__((address_space(3))) unsigned int*)(uint32_t)(uintptr_t)l,
      16, 0, 0);
}

// ---------------- gating: fp64-exact logits, top-2. NO ATOMICS (R9).
// The old version did 16384 atomicAdds on 8 counters sharing ONE 64B
// line -> fully serialized L2 RMWs ~= 170-200us hidden cost (invisible
// in top-5: gemm2's 5 iterations fill all slots). Scatter moved to a
// two-level histogram kernel below.
__global__ __launch_bounds__(256) void gate_kernel(
    const float* __restrict__ x, const float* __restrict__ gumbel,
    const float* __restrict__ gate_w, const float* __restrict__ gate_b,
    int* __restrict__ tok_e, float* __restrict__ tok_w)
{
  int t = blockIdx.x * 4 + (threadIdx.x >> 6);
  int lane = threadIdx.x & 63;
  const float* xr = x + (size_t)t * DMODEL;
  double acc[NEXP];
#pragma unroll
  for (int e = 0; e < NEXP; ++e) acc[e] = 0.0;
#pragma unroll
  for (int i = 0; i < DMODEL / 64; ++i) {
    int d = lane + i * 64;
    float xv = xr[d];
    const float4* gw = (const float4*)(gate_w + (size_t)d * NEXP);
    float4 g0 = gw[0], g1 = gw[1];
    acc[0] += (double)xv * (double)g0.x;
    acc[1] += (double)xv * (double)g0.y;
    acc[2] += (double)xv * (double)g0.z;
    acc[3] += (double)xv * (double)g0.w;
    acc[4] += (double)xv * (double)g1.x;
    acc[5] += (double)xv * (double)g1.y;
    acc[6] += (double)xv * (double)g1.z;
    acc[7] += (double)xv * (double)g1.w;
  }
#pragma unroll
  for (int e = 0; e < NEXP; ++e) {
    double v = acc[e];
    for (int off = 32; off > 0; off >>= 1) v += __shfl_down(v, off, 64);
    acc[e] = v;
  }
  if (lane == 0) {
    float noisy[NEXP];
#pragma unroll
    for (int e = 0; e < NEXP; ++e)
      noisy[e] = (float)(acc[e] + (double)gate_b[e]) + gumbel[(size_t)t * NEXP + e];
    int i0 = 0;
    for (int e = 1; e < NEXP; ++e) if (noisy[e] > noisy[i0]) i0 = e;
    int i1 = -1;
    for (int e = 0; e < NEXP; ++e) {
      if (e == i0) continue;
      if (i1 < 0 || noisy[e] > noisy[i1]) i1 = e;
    }
    float ex = expf(noisy[i1] - noisy[i0]);
    tok_e[2 * t] = i0; tok_w[2 * t] = 1.0f / (1.0f + ex);
    tok_e[2 * t + 1] = i1; tok_w[2 * t + 1] = ex / (1.0f + ex);
  }
}

// two-level scatter: LDS histogram + local rank, ONE global atomic per
// expert per block (32 blocks x 8 = 256 atomics on 64B-padded counters,
// vs 16384 same-line RMWs). Token order within an expert is permuted vs
// the old code, but per-row results are order-invariant.
__global__ __launch_bounds__(256) void scatter_kernel(
    const int* __restrict__ tok_e, int* __restrict__ cnt_pad,
    int* __restrict__ tok_p, int* __restrict__ tok_list)
{
  __shared__ int h[NEXP];
  __shared__ int base[NEXP];
  __shared__ int lr[512];
  int tid = threadIdx.x;
  if (tid < NEXP) h[tid] = 0;
  __syncthreads();
  int t = blockIdx.x * 256 + tid;
  int e0 = tok_e[2 * t], e1 = tok_e[2 * t + 1];
  lr[2 * tid]     = atomicAdd(&h[e0], 1);
  lr[2 * tid + 1] = atomicAdd(&h[e1], 1);
  __syncthreads();
  if (tid < NEXP) base[tid] = atomicAdd(&cnt_pad[tid * 16], h[tid]);
  __syncthreads();
  int p0 = base[e0] + lr[2 * tid];
  int p1 = base[e1] + lr[2 * tid + 1];
  tok_p[2 * t] = p0; tok_p[2 * t + 1] = p1;
  tok_list[e0 * T_TOKENS + p0] = t;
  tok_list[e1 * T_TOKENS + p1] = t;
}

// offsets + compact counts + live-block map: mb_map[i]=(e<<8)|bm, offs[8]=nb.
__global__ void offsets_kernel(const int* __restrict__ cnt_pad,
                               int* __restrict__ counts,
                               int* __restrict__ offs, int* __restrict__ mb_map) {
  if (threadIdx.x == 0 && blockIdx.x == 0) {
    int s = 0, nb = 0;
    for (int e = 0; e < NEXP; ++e) {
      int c = cnt_pad[e * 16];
      counts[e] = c;
      offs[e] = s; s += c;
      int nbe = (c + 255) >> 8;
      for (int b = 0; b < nbe; ++b) mb_map[nb++] = (e << 8) | b;
    }
    offs[8] = nb;
  }
}

__global__ __launch_bounds__(256) void slots_kernel(
    const int* __restrict__ offs, const int* __restrict__ tok_e,
    const int* __restrict__ tok_p, int* __restrict__ tok_slot)
{
  int i = blockIdx.x * 256 + threadIdx.x;
  if (i < 2 * T_TOKENS) tok_slot[i] = offs[tok_e[i]] + tok_p[i];
}

// ---------------- fp32 -> fp16 conversions -----------------------------------
__global__ __launch_bounds__(256) void cvt_f16_kernel(
    const float* __restrict__ in, u16* __restrict__ out, int n4)
{
  int i = blockIdx.x * 256 + threadIdx.x;
  if (i < n4) {
    float4 v = ((const float4*)in)[i];
    uint2 o;
    o.x = (unsigned)f2h(v.x) | ((unsigned)f2h(v.y) << 16);
    o.y = (unsigned)f2h(v.z) | ((unsigned)f2h(v.w) << 16);
    ((uint2*)out)[i] = o;
  }
}

// in [rows][cols] fp32 -> out [cols][rows] fp16, per-expert (blockIdx.z).
__global__ __launch_bounds__(256) void transpose_cvt_kernel(
    const float* __restrict__ in, u16* __restrict__ out, int rows, int cols)
{
  in  += (size_t)blockIdx.z * rows * cols;
  out += (size_t)blockIdx.z * rows * cols;
  int c0 = blockIdx.x * 64, r0 = blockIdx.y * 64;
  __shared__ u16 T[64][68];
  int tx = threadIdx.x & 15, ty = threadIdx.x >> 4;   // 16x16 threads
  int rr = ty * 4, cc = tx * 4;                       // 4x4 micro-tile
  const float* ip = &in[(size_t)(r0 + rr) * cols + (c0 + cc)];
  float4 v0 = *(const float4*)(ip);
  float4 v1 = *(const float4*)(ip + cols);
  float4 v2 = *(const float4*)(ip + 2 * (size_t)cols);
  float4 v3 = *(const float4*)(ip + 3 * (size_t)cols);
  const float* p0 = (const float*)&v0; const float* p1 = (const float*)&v1;
  const float* p2 = (const float*)&v2; const float* p3 = (const float*)&v3;
#pragma unroll
  for (int j = 0; j < 4; ++j) {
    union { u16 h[4]; unsigned u[2]; } pk;
    pk.h[0] = f2h(p0[j]); pk.h[1] = f2h(p1[j]);
    pk.h[2] = f2h(p2[j]); pk.h[3] = f2h(p3[j]);
    unsigned* dst = (unsigned*)&T[cc + j][rr];
    dst[0] = pk.u[0];
    dst[1] = pk.u[1];
  }
  __syncthreads();
  int oc = threadIdx.x >> 2;
  int orr = (threadIdx.x & 3) * 16;
  uint2 d0 = *(const uint2*)&T[oc][orr + 0];
  uint2 d1 = *(const uint2*)&T[oc][orr + 4];
  uint2 d2 = *(const uint2*)&T[oc][orr + 8];
  uint2 d3 = *(const uint2*)&T[oc][orr + 12];
  u16* op = &out[(size_t)(c0 + oc) * rows + (r0 + orr)];
  *(uint2*)(op + 0)  = d0;
  *(uint2*)(op + 4)  = d1;
  *(uint2*)(op + 8)  = d2;
  *(uint2*)(op + 12) = d3;
}

// =====================================================================
// 256x256 MFMA GEMMs: BK=32, 8 waves (2x4), 128x64 out/wave, 128KB quad
// buffer, single-barrier schedule (R7), full-rank XOR swizzle (R8;
// neutral — SQ_LDS_BANK_CONFLICT is b128 inherent accounting, ~4cyc/
// instr, identical across all 5 variants). GEMM path frozen this round.
// =====================================================================

// ---------------- GEMM1: H = relu(X[gather] @ W1 + b1), fp16 out -------------
__global__ __launch_bounds__(512, 2) void gemm1_kernel(
    const u16* __restrict__ xh, const u16* __restrict__ w1t,
    const float* __restrict__ b1,
    const int* __restrict__ counts, const int* __restrict__ offs,
    const int* __restrict__ mb_map,
    const int* __restrict__ tok_list, u16* __restrict__ H)
{
  const int L = blockIdx.x;                  // 1152 = 8 * 144
  const int W = (L & 7) * 144 + (L >> 3);    // XCD-contiguous work id
  const int bn = W / NBPAD;                  // 0..15
  const int mbi = W - bn * NBPAD;
  const int nb = offs[8];
  if (mbi >= nb) return;
  const int pk = mb_map[mbi];
  const int e = pk >> 8, bm = pk & 255;
  const int count = counts[e];
  const int off = offs[e];

  __shared__ __align__(16) u16 sm[4][2][8192];   // quad buffer: 128KB

  const int tid = threadIdx.x;
  const int w = tid >> 6, lane = tid & 63;
  const int wm = w >> 2, wn = w & 3;               // wave grid 2(M) x 4(N)
  const int row16 = lane & 15, quad = lane >> 4;
  const int r = lane >> 2;
  const int cg8 = (((lane & 3) ^ (r & 3) ^ ((r >> 2) & 3)) << 3);
  const int cm1 = count - 1;

  const u16* agA[2]; const u16* agB[2];
#pragma unroll
  for (int j = 0; j < 2; ++j) {
    int m = bm * 256 + w * 32 + j * 16 + r;        // 8 waves x 32 rows = 256
    int t = tok_list[e * T_TOKENS + (m < cm1 ? m : cm1)];
    agA[j] = xh + (size_t)t * DMODEL + cg8;
    int nrow = bn * 256 + w * 32 + j * 16 + r;
    agB[j] = w1t + ((size_t)e * DFF + nrow) * DMODEL + cg8;
  }
  const int ldsoff = w * 1024;                     // 32 rows * 32 cols per wave
  const int cslot = ((quad ^ (row16 & 3) ^ ((row16 >> 2) & 3)) << 3);

  f32x4 acc[8][4] = {};

#define STAGE1(k, b) { int ko = (k) << 5; \
    async16(agA[0] + ko, &sm[b][0][ldsoff]); \
    async16(agA[1] + ko, &sm[b][0][ldsoff + 512]); \
    async16(agB[0] + ko, &sm[b][1][ldsoff]); \
    async16(agB[1] + ko, &sm[b][1][ldsoff + 512]); }

  constexpr int NK = DMODEL / 32;   // 32
  STAGE1(0, 0); STAGE1(1, 1); STAGE1(2, 2);       // 12 loads in flight
  for (int k = 0; k < NK; ++k) {
    const int b = k & 3;
    asm volatile("s_waitcnt vmcnt(8)\n\ts_barrier" ::: "memory");
    STAGE1((k + 3) & (NK - 1), (k + 3) & 3);   // writes buf (k-1)&3: safe
    f16x8 af[8], bf[4];
#pragma unroll
    for (int f = 0; f < 8; ++f)
      af[f] = *(const f16x8*)&sm[b][0][(wm * 128 + f * 16 + row16) * 32 + cslot];
#pragma unroll
    for (int f = 0; f < 4; ++f)
      bf[f] = *(const f16x8*)&sm[b][1][(wn * 64 + f * 16 + row16) * 32 + cslot];
    __builtin_amdgcn_s_setprio(1);
#pragma unroll
    for (int fm = 0; fm < 8; ++fm)
#pragma unroll
      for (int fn = 0; fn < 4; ++fn)
        acc[fm][fn] = __builtin_amdgcn_mfma_f32_16x16x32_f16(bf[fn], af[fm], acc[fm][fn], 0, 0, 0);
    __builtin_amdgcn_s_setprio(0);
  }

  const int nb2 = bn * 256 + wn * 64 + quad * 4;
  const float* b1e = b1 + (size_t)e * DFF + nb2;
#pragma unroll
  for (int fm = 0; fm < 8; ++fm) {
    int m = bm * 256 + wm * 128 + fm * 16 + row16;
    if (m < count) {
      u16* hr = H + (size_t)(off + m) * DFF + nb2;
#pragma unroll
      for (int fn = 0; fn < 4; ++fn) {
        float4 bv = *(const float4*)(b1e + fn * 16);
        union { _Float16 h[4]; uint2 u; } pk2;
        float v0 = acc[fm][fn][0] + bv.x; pk2.h[0] = (_Float16)(v0 > 0.f ? v0 : 0.f);
        float v1 = acc[fm][fn][1] + bv.y; pk2.h[1] = (_Float16)(v1 > 0.f ? v1 : 0.f);
        float v2 = acc[fm][fn][2] + bv.z; pk2.h[2] = (_Float16)(v2 > 0.f ? v2 : 0.f);
        float v3 = acc[fm][fn][3] + bv.w; pk2.h[3] = (_Float16)(v3 > 0.f ? v3 : 0.f);
        *(uint2*)(hr + fn * 16) = pk2.u;
      }
    }
  }
}

// ---------------- GEMM2: P[slot] = H[slot] @ W2 + b2 (fp32, coalesced) -------
__global__ __launch_bounds__(512, 2) void gemm2_kernel(
    const u16* __restrict__ H, const u16* __restrict__ w2t,
    const float* __restrict__ b2,
    const int* __restrict__ counts, const int* __restrict__ offs,
    const int* __restrict__ mb_map,
    float* __restrict__ P)
{
  const int L = blockIdx.x;                  // 288 = 8 * 36
  const int W = (L & 7) * 36 + (L >> 3);     // XCD-contiguous work id
  const int mbi = W >> 2, bn = W & 3;        // 4 bn-siblings contiguous
  const int nb = offs[8];
  if (mbi >= nb) return;
  const int pk = mb_map[mbi];
  const int e = pk >> 8, bm = pk & 255;
  const int count = counts[e];
  const int off = offs[e];

  __shared__ __align__(16) u16 sm[4][2][8192];   // quad buffer: 128KB

  const int tid = threadIdx.x;
  const int w = tid >> 6, lane = tid & 63;
  const int wm = w >> 2, wn = w & 3;
  const int row16 = lane & 15, quad = lane >> 4;
  const int r = lane >> 2;
  const int cg8 = (((lane & 3) ^ (r & 3) ^ ((r >> 2) & 3)) << 3);
  const int cm1 = count - 1;

  const u16* agA[2]; const u16* agB[2];
#pragma unroll
  for (int j = 0; j < 2; ++j) {
    int m = bm * 256 + w * 32 + j * 16 + r;
    agA[j] = H + (size_t)(off + (m < cm1 ? m : cm1)) * DFF + cg8;
    int nrow = bn * 256 + w * 32 + j * 16 + r;
    agB[j] = w2t + ((size_t)e * DMODEL + nrow) * DFF + cg8;
  }
  const int ldsoff = w * 1024;
  const int cslot = ((quad ^ (row16 & 3) ^ ((row16 >> 2) & 3)) << 3);

  f32x4 acc[8][4] = {};

  constexpr int NK = DFF / 32;   // 128
  STAGE1(0, 0); STAGE1(1, 1); STAGE1(2, 2);       // 12 loads in flight
  for (int k = 0; k < NK; ++k) {
    const int b = k & 3;
    asm volatile("s_waitcnt vmcnt(8)\n\ts_barrier" ::: "memory");
    STAGE1((k + 3) & (NK - 1), (k + 3) & 3);   // writes buf (k-1)&3: safe
    f16x8 af[8], bf[4];
#pragma unroll
    for (int f = 0; f < 8; ++f)
      af[f] = *(const f16x8*)&sm[b][0][(wm * 128 + f * 16 + row16) * 32 + cslot];
#pragma unroll
    for (int f = 0; f < 4; ++f)
      bf[f] = *(const f16x8*)&sm[b][1][(wn * 64 + f * 16 + row16) * 32 + cslot];
    __builtin_amdgcn_s_setprio(1);
#pragma unroll
    for (int fm = 0; fm < 8; ++fm)
#pragma unroll
      for (int fn = 0; fn < 4; ++fn)
        acc[fm][fn] = __builtin_amdgcn_mfma_f32_16x16x32_f16(bf[fn], af[fm], acc[fm][fn], 0, 0, 0);
    __builtin_amdgcn_s_setprio(0);
  }

  const int nb2 = bn * 256 + wn * 64 + quad * 4;
  const float* b2e = b2 + (size_t)e * DMODEL + nb2;
#pragma unroll
  for (int fm = 0; fm < 8; ++fm) {
    int m = bm * 256 + wm * 128 + fm * 16 + row16;
    if (m < count) {
      float* pr = P + (size_t)(off + m) * DMODEL + nb2;
#pragma unroll
      for (int fn = 0; fn < 4; ++fn) {
        float4 bv = *(const float4*)(b2e + fn * 16);
        float4 o;
        o.x = acc[fm][fn][0] + bv.x;
        o.y = acc[fm][fn][1] + bv.y;
        o.z = acc[fm][fn][2] + bv.z;
        o.w = acc[fm][fn][3] + bv.w;
        *(float4*)(pr + fn * 16) = o;
      }
    }
  }
}

// ---------------- combine: out[t] = w0*P[s0] + w1*P[s1] ----------------------
__global__ __launch_bounds__(256) void combine_kernel(
    const float* __restrict__ P, const int* __restrict__ tok_slot,
    const float* __restrict__ tok_w, float* __restrict__ out)
{
  int idx = blockIdx.x * 256 + threadIdx.x;
  int t = idx >> 8;
  int d = (idx & 255) << 2;
  int s0 = tok_slot[2 * t], s1 = tok_slot[2 * t + 1];
  float w0 = tok_w[2 * t], w1 = tok_w[2 * t + 1];
  float4 a = *(const float4*)(P + (size_t)s0 * DMODEL + d);
  float4 b = *(const float4*)(P + (size_t)s1 * DMODEL + d);
  float4 o;
  o.x = w0 * a.x + w1 * b.x;
  o.y = w0 * a.y + w1 * b.y;
  o.z = w0 * a.z + w1 * b.z;
  o.w = w0 * a.w + w1 * b.w;
  *(float4*)(out + (size_t)t * DMODEL + d) = o;
}

// ---------------- launch -----------------------------------------------------
extern "C" void kernel_launch(void* const* d_in, const int* in_sizes, int n_in,
                              void* d_out, int out_size, void* d_ws, size_t ws_size,
                              hipStream_t stream)
{
  const float* x      = (const float*)d_in[0];
  const float* gumbel = (const float*)d_in[1];
  const float* gate_w = (const float*)d_in[2];
  const float* gate_b = (const float*)d_in[3];
  const float* w1     = (const float*)d_in[4];
  const float* b1     = (const float*)d_in[5];
  const float* w2     = (const float*)d_in[6];
  const float* b2     = (const float*)d_in[7];
  float* out = (float*)d_out;
  char* ws = (char*)d_ws;

  // workspace layout (~286 MB; P overlays dead w1t region)
  constexpr size_t OFF_CNTP   = 0;       // 8 x 64B-padded counters (512B, memset)
  constexpr size_t OFF_COUNTS = 512;     // compact counts[8]
  constexpr size_t OFF_OFFS   = 576;     // offs[9]
  constexpr size_t OFF_MAP    = 640;     // mb_map[<=80]
  constexpr size_t OFF_TOK    = 4096;
  constexpr size_t OFF_TE     = OFF_TOK + (size_t)NEXP * T_TOKENS * 4;
  constexpr size_t OFF_TP     = OFF_TE + 2 * T_TOKENS * 4;
  constexpr size_t OFF_TW     = OFF_TP + 2 * T_TOKENS * 4;
  constexpr size_t OFF_TS     = OFF_TW + 2 * T_TOKENS * 4;
  constexpr size_t OFF_XH     = OFF_TS + 2 * T_TOKENS * 4;
  constexpr size_t OFF_W1T    = OFF_XH  + (size_t)T_TOKENS * DMODEL * 2;
  constexpr size_t OFF_W2T    = OFF_W1T + (size_t)NEXP * DFF * DMODEL * 2;
  constexpr size_t OFF_H      = OFF_W2T + (size_t)NEXP * DMODEL * DFF * 2;
  constexpr size_t OFF_P      = OFF_W1T;  // w1t dead after gemm1

  int*   cnt_pad = (int*)(ws + OFF_CNTP);
  int*   counts  = (int*)(ws + OFF_COUNTS);
  int*   offs    = (int*)(ws + OFF_OFFS);
  int*   mb_map  = (int*)(ws + OFF_MAP);
  int*   tokl    = (int*)(ws + OFF_TOK);
  int*   tok_e   = (int*)(ws + OFF_TE);
  int*   tok_p   = (int*)(ws + OFF_TP);
  float* tok_w   = (float*)(ws + OFF_TW);
  int*   tok_s   = (int*)(ws + OFF_TS);
  u16*   xh      = (u16*)(ws + OFF_XH);
  u16*   w1t     = (u16*)(ws + OFF_W1T);
  u16*   w2t     = (u16*)(ws + OFF_W2T);
  u16*   H       = (u16*)(ws + OFF_H);
  float* P       = (float*)(ws + OFF_P);

  hipMemsetAsync(ws + OFF_CNTP, 0, 1024, stream);

  cvt_f16_kernel<<<(T_TOKENS * DMODEL / 4 + 255) / 256, 256, 0, stream>>>(
      x, xh, T_TOKENS * DMODEL / 4);
  transpose_cvt_kernel<<<dim3(DFF / 64, DMODEL / 64, NEXP), 256, 0, stream>>>(
      w1, w1t, DMODEL, DFF);
  transpose_cvt_kernel<<<dim3(DMODEL / 64, DFF / 64, NEXP), 256, 0, stream>>>(
      w2, w2t, DFF, DMODEL);
  gate_kernel<<<T_TOKENS / 4, 256, 0, stream>>>(
      x, gumbel, gate_w, gate_b, tok_e, tok_w);
  scatter_kernel<<<T_TOKENS / 256, 256, 0, stream>>>(
      tok_e, cnt_pad, tok_p, tokl);
  offsets_kernel<<<1, 64, 0, stream>>>(cnt_pad, counts, offs, mb_map);
  slots_kernel<<<(2 * T_TOKENS + 255) / 256, 256, 0, stream>>>(
      offs, tok_e, tok_p, tok_s);
  gemm1_kernel<<<NBPAD * 16, 512, 0, stream>>>(
      xh, w1t, b1, counts, offs, mb_map, tokl, H);
  gemm2_kernel<<<NBPAD * 4, 512, 0, stream>>>(
      H, w2t, b2, counts, offs, mb_map, P);
  combine_kernel<<<T_TOKENS, 256, 0, stream>>>(P, tok_s, tok_w, out);
}